// Round 8
// baseline (632.880 us; speedup 1.0000x reference)
//
#include <hip/hip_runtime.h>
#include <math.h>

#define DM   1024   // DMODEL
#define DI   2048   // D_INNER
#define DSn  16     // D_STATE
#define DTR  64     // DT_RANK
#define PW   96     // DT_RANK + 2*D_STATE
#define LS   1024   // per-mamba sequence length
#define NCH  16     // scan time-chunks
#define CL   64     // chunk length (LS/NCH)
#define XKS  4      // xproj K-slices

typedef unsigned short u16;
typedef unsigned int   u32;
typedef __attribute__((ext_vector_type(8))) short bf16x8;
typedef __attribute__((ext_vector_type(8))) unsigned short u16x8;
typedef __attribute__((ext_vector_type(4))) float f32x4;

// LDS-only barrier: waits ds-ops but leaves in-flight global loads un-drained.
__device__ __forceinline__ void bar_lds() {
  asm volatile("s_waitcnt lgkmcnt(0)\n\ts_barrier" ::: "memory");
}

// truncation hi/lo split: hi = trunc-to-bf16(f), lo = trunc-to-bf16(f - hi).
__device__ __forceinline__ void split2(float f, u16& hi, u16& lo) {
  union { float f; unsigned int u; } v; v.f = f;
  hi = (u16)(v.u >> 16);
  union { unsigned int u; float f; } w; w.u = v.u & 0xffff0000u;
  union { float f; unsigned int u; } r; r.f = f - w.f;
  lo = (u16)(r.u >> 16);
}

template<int ROWS>
__device__ __forceinline__ bf16x8 frag(const u16* T, int l4, int row) {
  return *(const bf16x8*)&T[(l4 * ROWS + row) * 8];
}

// stage 16 f32 into hi/lo planes (two k-groups of 8) at rows [ra], halves
template<int ROWS>
__device__ __forceinline__ void stage16f(const float* a, u16* Th, u16* Tl, int ra, int half) {
  #pragma unroll
  for (int q = 0; q < 2; ++q) {
    u16x8 vh, vl;
    #pragma unroll
    for (int c = 0; c < 8; ++c) {
      u16 h_, l_;
      split2(a[q * 8 + c], h_, l_);
      vh[c] = h_; vl[c] = l_;
    }
    const int slot = ((half * 2 + q) * ROWS + ra) * 8;
    *(u16x8*)&Th[slot] = vh;
    *(u16x8*)&Tl[slot] = vl;
  }
}

// x tokens -> token-ordered planes xh/xl [nt][1024] (local t)
__global__ __launch_bounds__(256) void k_split_x(
    const float* __restrict__ x, u16* __restrict__ xh, u16* __restrict__ xl, int ib0)
{
  const int idx = blockIdx.x * 256 + threadIdx.x;
  const int t = idx >> 8, kq = (idx & 255) * 4;
  const int gt = ib0 * 1024 + t;
  const int j = gt & (LS - 1), ib = gt >> 10;
  const int i = ib >> 1, bb = ib & 1;
  const float4 v = *(const float4*)&x[(size_t)(bb * 4096 + j * 4 + i) * DM + kq];
  ushort4 vh, vl;
  split2(v.x, vh.x, vl.x); split2(v.y, vh.y, vl.y);
  split2(v.z, vh.z, vl.z); split2(v.w, vh.w, vl.w);
  *(ushort4*)&xh[(size_t)t * DM + kq] = vh;
  *(ushort4*)&xl[(size_t)t * DM + kq] = vl;
}

// ---------------- in-proj: xz[t][e] = x_tok(t) . in_w[i][e]  (N=4096, K=1024)
// 128x128 tile, 256 threads (4 waves 2x2, wave owns 64x64). SINGLE-buffer LDS
// (33 KB -> ~3 blocks/CU), two lgkm-only barriers per K-step (WAR+visibility);
// kt+1 regs staged, kt+2 global loads in flight across barriers.
// [guide tile table: 128^2 pairs with simple 2-barrier loops]
#define KGQ 1040    // u16 per k-group slice: 128*8 + 16 pad (bank stagger 8/kg)
__global__ __launch_bounds__(256, 3) void k_inproj(
    const u16* __restrict__ xh, const u16* __restrict__ xl,
    const float* __restrict__ inwf,
    float* __restrict__ xz, int ib0, int swz)
{
  __shared__ __align__(16) u16 Ah[4*KGQ], Al[4*KGQ], Bh[4*KGQ], Bl[4*KGQ]; // 33280 B
  const int tid = threadIdx.x;
  int mblk, nblk;
  if (swz) {
    const int o = blockIdx.x;          // 0..2047 = 64 mblk x 32 nblk
    const int xcd = o & 7, within = o >> 3;   // within 0..255
    mblk = xcd * 8 + (within & 7);     // each XCD owns one ib (8 mblks, A=4MB=L2)
    nblk = within >> 3;                // 0..31
  } else {
    mblk = blockIdx.x; nblk = blockIdx.y;
  }
  const int m0 = mblk << 7, n0 = nblk << 7;
  const int ib = ib0 + (m0 >> 10);
  const int il = (ib >> 1) - (ib0 >> 1);
  const int ra = tid >> 1, half = tid & 1;      // 128 rows x 2 k-halves
  const u16* Aph = xh + (size_t)(m0 + ra) * DM + half * 16;
  const u16* Apl = xl + (size_t)(m0 + ra) * DM + half * 16;
  const float* Bpf = inwf + ((size_t)il * 4096 + n0 + ra) * DM + half * 16;
  const int w = tid >> 6, lane = tid & 63;
  const int wr = w >> 1, wc = w & 1;            // wave grid 2 x 2
  const int l15 = lane & 15, l4 = lane >> 4;

  f32x4 acc[4][4];
  #pragma unroll
  for (int a_ = 0; a_ < 4; ++a_)
    #pragma unroll
    for (int b_ = 0; b_ < 4; ++b_) acc[a_][b_] = (f32x4)(0.f);

  u16x8 ah2[2], al2[2];
  float br[16];

  auto LOADG = [&](int kt) {
    const int k0 = kt * 32;
    ah2[0] = *(const u16x8*)(Aph + k0);
    ah2[1] = *(const u16x8*)(Aph + k0 + 8);
    al2[0] = *(const u16x8*)(Apl + k0);
    al2[1] = *(const u16x8*)(Apl + k0 + 8);
    *(f32x4*)&br[0]  = *(const f32x4*)(Bpf + k0);
    *(f32x4*)&br[4]  = *(const f32x4*)(Bpf + k0 + 4);
    *(f32x4*)&br[8]  = *(const f32x4*)(Bpf + k0 + 8);
    *(f32x4*)&br[12] = *(const f32x4*)(Bpf + k0 + 12);
  };
  auto STORE = [&]() {
    #pragma unroll
    for (int q = 0; q < 2; ++q) {
      const int kg = half * 2 + q;
      *(u16x8*)&Ah[kg * KGQ + ra * 8] = ah2[q];
      *(u16x8*)&Al[kg * KGQ + ra * 8] = al2[q];
      u16x8 vh, vl;
      #pragma unroll
      for (int c = 0; c < 8; ++c) {
        u16 h_, l_;
        split2(br[q * 8 + c], h_, l_);
        vh[c] = h_; vl[c] = l_;
      }
      *(u16x8*)&Bh[kg * KGQ + ra * 8] = vh;
      *(u16x8*)&Bl[kg * KGQ + ra * 8] = vl;
    }
  };
  auto COMPUTE = [&]() {
    bf16x8 bh[4], bl[4];
    #pragma unroll
    for (int nf = 0; nf < 4; ++nf) {
      const int col = wc * 64 + nf * 16 + l15;
      bh[nf] = *(const bf16x8*)&Bh[l4 * KGQ + col * 8];
      bl[nf] = *(const bf16x8*)&Bl[l4 * KGQ + col * 8];
    }
    #pragma unroll
    for (int mf = 0; mf < 4; ++mf) {
      const int row = wr * 64 + mf * 16 + l15;
      bf16x8 ah = *(const bf16x8*)&Ah[l4 * KGQ + row * 8];
      bf16x8 al = *(const bf16x8*)&Al[l4 * KGQ + row * 8];
      #pragma unroll
      for (int nf = 0; nf < 4; ++nf) {
        acc[mf][nf] = __builtin_amdgcn_mfma_f32_16x16x32_bf16(ah, bh[nf], acc[mf][nf], 0, 0, 0);
        acc[mf][nf] = __builtin_amdgcn_mfma_f32_16x16x32_bf16(ah, bl[nf], acc[mf][nf], 0, 0, 0);
        acc[mf][nf] = __builtin_amdgcn_mfma_f32_16x16x32_bf16(al, bh[nf], acc[mf][nf], 0, 0, 0);
      }
    }
  };

  const int nk = DM / 32;   // 32
  LOADG(0);
  STORE();
  bar_lds();                // visibility of tile 0
  LOADG(1);
  for (int kt = 0; kt < nk; ++kt) {
    COMPUTE();
    if (kt + 1 < nk) {
      bar_lds();            // WAR: all frag reads retired
      STORE();              // stage kt+1 from regs
      bar_lds();            // visibility
      if (kt + 2 < nk) LOADG(kt + 2);   // stays in flight across barriers
    }
  }

  #pragma unroll
  for (int mf = 0; mf < 4; ++mf) {
    const int row = m0 + wr * 64 + mf * 16 + l4 * 4;
    #pragma unroll
    for (int nf = 0; nf < 4; ++nf) {
      const int col = n0 + wc * 64 + nf * 16 + l15;
      #pragma unroll
      for (int r = 0; r < 4; ++r)
        xz[(size_t)(row + r) * (2 * DI) + col] = acc[mf][nf][r];
    }
  }
}

// ---------------- conv + silu -> xib f32 ----------------
__global__ __launch_bounds__(256) void k_conv(
    const float* __restrict__ xz, const float* __restrict__ convw,
    const float* __restrict__ convb, float* __restrict__ xib,
    int ib0, int ntok)
{
  const int idx = blockIdx.x * 256 + threadIdx.x;
  if (idx >= ntok * (DI / 4)) return;
  const int t = idx / (DI / 4);
  const int c = (idx - t * (DI / 4)) * 4;
  const int j = t & (LS - 1);
  const int i = (ib0 + (t >> 10)) >> 1;
  float4 acc = *(const float4*)&convb[(size_t)i * DI + c];
  float4 wt[4];
  #pragma unroll
  for (int q = 0; q < 4; ++q)
    wt[q] = *(const float4*)&convw[((size_t)i * DI + c + q) * 4];
  #pragma unroll
  for (int k = 0; k < 4; ++k) {
    const int j2 = j + k - 3;
    if (j2 >= 0) {
      const float4 v = *(const float4*)&xz[(size_t)(t + k - 3) * (2 * DI) + c];
      acc.x = fmaf(v.x, ((const float*)&wt[0])[k], acc.x);
      acc.y = fmaf(v.y, ((const float*)&wt[1])[k], acc.y);
      acc.z = fmaf(v.z, ((const float*)&wt[2])[k], acc.z);
      acc.w = fmaf(v.w, ((const float*)&wt[3])[k], acc.w);
    }
  }
  float4 o;
  o.x = acc.x / (1.f + __expf(-acc.x));
  o.y = acc.y / (1.f + __expf(-acc.y));
  o.z = acc.z / (1.f + __expf(-acc.z));
  o.w = acc.w / (1.f + __expf(-acc.w));
  *(float4*)&xib[(size_t)t * DI + c] = o;
}

// ---------------- xproj part: A from xi f32, B from xproj_w f32 ------------
// Double-buffered (40 KB), ONE bar_lds per K-step, kt+2 reg prefetch.
__global__ __launch_bounds__(256) void k_xproj_part(
    const float* __restrict__ xif, const float* __restrict__ xwf,
    float* __restrict__ Pp, int ib0, int ntok)
{
  __shared__ __align__(16) u16 Ah[2][4*64*8], Al[2][4*64*8];
  __shared__ __align__(16) u16 Bh[2][4*96*8], Bl[2][4*96*8];
  const int tid = threadIdx.x;
  const int m0 = blockIdx.x << 6;
  const int ks = blockIdx.y;
  const int kbase = ks * (DI / XKS);
  const int ib = ib0 + (m0 >> 10);
  const int il = (ib >> 1) - (ib0 >> 1);
  const int ra = tid >> 1, half = tid & 1;
  const bool hasA = (tid < 128);
  const bool hasB = (tid < 192);
  const float* Apf = xif + (size_t)(m0 + ra) * DI + kbase + half * 16;
  const float* Bpf = xwf + ((size_t)il * PW + ra) * DI + kbase + half * 16;
  const int w = tid >> 6, lane = tid & 63;
  const int l15 = lane & 15, l4 = lane >> 4;

  f32x4 acc[6];
  #pragma unroll
  for (int b_ = 0; b_ < 6; ++b_) acc[b_] = (f32x4)(0.f);

  float ar[16], br[16];
  auto LOADAB = [&](int kt) {
    const int k0 = kt * 32;
    if (hasA) {
      #pragma unroll
      for (int q = 0; q < 4; ++q) *(f32x4*)&ar[q*4] = *(const f32x4*)(Apf + k0 + q*4);
    }
    if (hasB) {
      #pragma unroll
      for (int q = 0; q < 4; ++q) *(f32x4*)&br[q*4] = *(const f32x4*)(Bpf + k0 + q*4);
    }
  };
  auto STORE = [&](int b) {
    if (hasA) stage16f<64>(ar, Ah[b], Al[b], ra, half);
    if (hasB) stage16f<96>(br, Bh[b], Bl[b], ra, half);
  };
  auto COMPUTE = [&](int b) {
    const int arow = w * 16 + l15;
    bf16x8 ah = frag<64>(Ah[b], l4, arow);
    bf16x8 al = frag<64>(Al[b], l4, arow);
    #pragma unroll
    for (int nf = 0; nf < 6; ++nf) {
      const int col = nf * 16 + l15;
      bf16x8 bh = frag<96>(Bh[b], l4, col);
      bf16x8 bl = frag<96>(Bl[b], l4, col);
      acc[nf] = __builtin_amdgcn_mfma_f32_16x16x32_bf16(ah, bh, acc[nf], 0, 0, 0);
      acc[nf] = __builtin_amdgcn_mfma_f32_16x16x32_bf16(ah, bl, acc[nf], 0, 0, 0);
      acc[nf] = __builtin_amdgcn_mfma_f32_16x16x32_bf16(al, bh, acc[nf], 0, 0, 0);
    }
  };

  const int nk = (DI / XKS) / 32;   // 16
  LOADAB(0);
  STORE(0);
  LOADAB(1);
  bar_lds();
  for (int kt = 0; kt < nk; ++kt) {
    const int c = kt & 1;
    if (kt + 1 < nk) STORE(c ^ 1);
    if (kt + 2 < nk) LOADAB(kt + 2);
    COMPUTE(c);
    bar_lds();
  }

  float* outp = Pp + (size_t)ks * ntok * PW;
  const int row = m0 + w * 16 + l4 * 4;
  #pragma unroll
  for (int nf = 0; nf < 6; ++nf) {
    const int col = nf * 16 + l15;
    #pragma unroll
    for (int r = 0; r < 4; ++r)
      outp[(size_t)(row + r) * PW + col] = acc[nf][r];
  }
}

// ---------------- xproj reduce ----------------
__global__ __launch_bounds__(256) void k_xproj_red(
    const float* __restrict__ Pp, float* __restrict__ projb, int ntok)
{
  const int idx = blockIdx.x * 256 + threadIdx.x;
  if (idx >= ntok * PW) return;
  const size_t plane = (size_t)ntok * PW;
  float s = 0.f;
  #pragma unroll
  for (int ks = 0; ks < XKS; ++ks) s += Pp[(size_t)ks * plane + idx];
  projb[idx] = s;
}

// ---------------- dt GEMM (MFMA hi/lo) + softplus -> dtout[t*dstride + d] --
// M=ntok (by: 128-token tile), N=DI (bx: 128-d tile), K=DTR=64.
// Single staging pass (K fits in LDS), one barrier, 96 MFMA/wave.
__global__ __launch_bounds__(256) void k_dtproj(
    const float* __restrict__ proj, const float* __restrict__ dtw,
    const float* __restrict__ dtbias, float* __restrict__ dtout,
    int dstride, int ib0)
{
  __shared__ __align__(16) u16 Ah[8*128*8], Al[8*128*8];   // 16 KB each
  __shared__ __align__(16) u16 Bh[8*128*8], Bl[8*128*8];
  const int tid = threadIdx.x;
  const int n0 = blockIdx.x << 7;
  const int m0 = blockIdx.y << 7;
  const int ib = ib0 + (m0 >> 10);
  const int i  = ib >> 1;
  const int ra = tid >> 1, half = tid & 1;   // 128 rows x 2 k-halves (32 each)
  const float* Ap = proj + (size_t)(m0 + ra) * PW + half * 32;
  const float* Bp = dtw + ((size_t)i * DI + n0 + ra) * DTR + half * 32;
  const int w = tid >> 6, lane = tid & 63;
  const int wr = w >> 1, wc = w & 1;         // wave grid 2 x 2, wave owns 64x64
  const int l15 = lane & 15, l4 = lane >> 4;

  {
    float av[32], bv[32];
    #pragma unroll
    for (int q = 0; q < 8; ++q) *(f32x4*)&av[q*4] = *(const f32x4*)(Ap + q*4);
    #pragma unroll
    for (int q = 0; q < 8; ++q) *(f32x4*)&bv[q*4] = *(const f32x4*)(Bp + q*4);
    #pragma unroll
    for (int q = 0; q < 4; ++q) {
      u16x8 vh, vl, wh, wl;
      #pragma unroll
      for (int c = 0; c < 8; ++c) {
        u16 h_, l_;
        split2(av[q*8+c], h_, l_); vh[c] = h_; vl[c] = l_;
        split2(bv[q*8+c], h_, l_); wh[c] = h_; wl[c] = l_;
      }
      const int slot = ((half*4 + q) * 128 + ra) * 8;
      *(u16x8*)&Ah[slot] = vh; *(u16x8*)&Al[slot] = vl;
      *(u16x8*)&Bh[slot] = wh; *(u16x8*)&Bl[slot] = wl;
    }
  }
  __syncthreads();

  f32x4 acc[4][4];
  #pragma unroll
  for (int a_ = 0; a_ < 4; ++a_)
    #pragma unroll
    for (int b_ = 0; b_ < 4; ++b_) acc[a_][b_] = (f32x4)(0.f);

  #pragma unroll
  for (int c = 0; c < 2; ++c) {              // K-chunk of 32: kgroups 4c+l4
    bf16x8 bh[4], bl[4];
    #pragma unroll
    for (int nf = 0; nf < 4; ++nf) {
      const int col = wc * 64 + nf * 16 + l15;
      bh[nf] = *(const bf16x8*)&Bh[((4*c + l4) * 128 + col) * 8];
      bl[nf] = *(const bf16x8*)&Bl[((4*c + l4) * 128 + col) * 8];
    }
    #pragma unroll
    for (int mf = 0; mf < 4; ++mf) {
      const int row = wr * 64 + mf * 16 + l15;
      bf16x8 ah = *(const bf16x8*)&Ah[((4*c + l4) * 128 + row) * 8];
      bf16x8 al = *(const bf16x8*)&Al[((4*c + l4) * 128 + row) * 8];
      #pragma unroll
      for (int nf = 0; nf < 4; ++nf) {
        acc[mf][nf] = __builtin_amdgcn_mfma_f32_16x16x32_bf16(ah, bh[nf], acc[mf][nf], 0, 0, 0);
        acc[mf][nf] = __builtin_amdgcn_mfma_f32_16x16x32_bf16(ah, bl[nf], acc[mf][nf], 0, 0, 0);
        acc[mf][nf] = __builtin_amdgcn_mfma_f32_16x16x32_bf16(al, bh[nf], acc[mf][nf], 0, 0, 0);
      }
    }
  }

  #pragma unroll
  for (int nf = 0; nf < 4; ++nf) {
    const int col = n0 + wc * 64 + nf * 16 + l15;
    const float bias = dtbias[(size_t)i * DI + col];
    #pragma unroll
    for (int mf = 0; mf < 4; ++mf) {
      const int t0 = m0 + wr * 64 + mf * 16 + l4 * 4;
      #pragma unroll
      for (int r = 0; r < 4; ++r) {
        const float u = acc[mf][nf][r] + bias;
        const float sp = (u > 20.f) ? u : log1pf(__expf(u));
        dtout[(size_t)(t0 + r) * dstride + col] = sp;
      }
    }
  }
}

// ---------------- scan phase A ----------------
__global__ __launch_bounds__(256) void k_scan_part(
    const float* __restrict__ projb, const float* dtp, int dstride,
    const float* __restrict__ xib, const float* __restrict__ A_log,
    float* __restrict__ Pbuf, float* __restrict__ Hbuf, int ib0)
{
  const int d = blockIdx.x * 256 + threadIdx.x;
  const int ch = blockIdx.y, lib = blockIdx.z;
  const int i = (ib0 + lib) >> 1;
  const size_t gd = (size_t)i * DI + d;
  __shared__ float bs[CL][DSn];
  const size_t trow = (size_t)lib * LS + (size_t)ch * CL;
  for (int p = threadIdx.x; p < CL * DSn; p += 256) {
    const int jj = p >> 4, ss = p & 15;
    bs[jj][ss] = projb[(trow + jj) * PW + DTR + ss];
  }
  float A[DSn], P[DSn], h[DSn];
  #pragma unroll
  for (int s = 0; s < DSn; ++s) {
    A[s] = -__expf(A_log[gd * DSn + s]);
    P[s] = 1.f; h[s] = 0.f;
  }
  __syncthreads();
  float dt_c = dtp[trow * dstride + d];
  float xi_c = xib[trow * DI + d];
  for (int j = 0; j < CL; ++j) {
    float dt_n = 0.f, xi_n = 0.f;
    if (j + 1 < CL) {
      dt_n = dtp[(trow + j + 1) * dstride + d];
      xi_n = xib[(trow + j + 1) * DI + d];
    }
    const float dx = dt_c * xi_c;
    #pragma unroll
    for (int s = 0; s < DSn; ++s) {
      const float dA = __expf(dt_c * A[s]);
      P[s] *= dA;
      h[s] = fmaf(dA, h[s], dx * bs[j][s]);
    }
    dt_c = dt_n; xi_c = xi_n;
  }
  const size_t base = ((size_t)(lib * NCH + ch) * DSn) * DI + d;
  #pragma unroll
  for (int s = 0; s < DSn; ++s) {
    Pbuf[base + (size_t)s * DI] = P[s];
    Hbuf[base + (size_t)s * DI] = h[s];
  }
}

// ---------------- scan phase B ----------------
__global__ __launch_bounds__(256) void k_scan_mid(
    float* __restrict__ Pbuf, const float* __restrict__ Hbuf, int nib)
{
  const int idx = blockIdx.x * 256 + threadIdx.x;
  if (idx >= nib * DSn * DI) return;
  const int d = idx & (DI - 1);
  const int s = (idx >> 11) & 15;
  const int lib = idx >> 15;
  const size_t stride = (size_t)DSn * DI;
  const size_t base = ((size_t)lib * NCH * DSn + s) * DI + d;
  float carry = 0.f;
  for (int c = 0; c < NCH; ++c) {
    const size_t o = base + (size_t)c * stride;
    const float p = Pbuf[o];
    const float hl = Hbuf[o];
    Pbuf[o] = carry;
    carry = fmaf(p, carry, hl);
  }
}

// ---------------- scan phase C: gated y packed (bf16 hi|lo) IN-PLACE over xi
__global__ __launch_bounds__(256) void k_scan_full(
    const float* __restrict__ projb, const float* dtp, int dstride,
    float* xibio, const float* xzz,
    const float* __restrict__ A_log, const float* __restrict__ D_skip,
    const float* __restrict__ Pbuf, int ib0)
{
  const int d = blockIdx.x * 256 + threadIdx.x;
  const int ch = blockIdx.y, lib = blockIdx.z;
  const int i = (ib0 + lib) >> 1;
  const size_t gd = (size_t)i * DI + d;
  __shared__ float bs[CL][2 * DSn];
  const size_t trow = (size_t)lib * LS + (size_t)ch * CL;
  for (int p = threadIdx.x; p < CL * 2 * DSn; p += 256) {
    const int jj = p >> 5, ss = p & 31;
    bs[jj][ss] = projb[(trow + jj) * PW + DTR + ss];
  }
  float A[DSn], h[DSn];
  const size_t hbase = ((size_t)(lib * NCH + ch) * DSn) * DI + d;
  #pragma unroll
  for (int s = 0; s < DSn; ++s) {
    A[s] = -__expf(A_log[gd * DSn + s]);
    h[s] = Pbuf[hbase + (size_t)s * DI];
  }
  const float Dsk = D_skip[gd];
  __syncthreads();
  float dt_c = dtp[trow * dstride + d];
  float xi_c = xibio[trow * DI + d];
  float z_c  = xzz[trow * (2 * DI) + DI + d];
  for (int j = 0; j < CL; ++j) {
    float dt_n = 0.f, xi_n = 0.f, z_n = 0.f;
    if (j + 1 < CL) {
      dt_n = dtp[(trow + j + 1) * dstride + d];
      xi_n = xibio[(trow + j + 1) * DI + d];
      z_n  = xzz[(trow + j + 1) * (2 * DI) + DI + d];
    }
    const float dx = dt_c * xi_c;
    float y = 0.f;
    #pragma unroll
    for (int s = 0; s < DSn; ++s) {
      const float dA = __expf(dt_c * A[s]);
      h[s] = fmaf(dA, h[s], dx * bs[j][s]);
      y = fmaf(h[s], bs[j][DSn + s], y);
    }
    const float sz = z_c / (1.f + __expf(-z_c));
    const float val = (y + xi_c * Dsk) * sz;
    u16 vh, vl;
    split2(val, vh, vl);
    ((u32*)xibio)[(trow + j) * DI + d] = ((u32)vh << 16) | (u32)vl;
    dt_c = dt_n; xi_c = xi_n; z_c = z_n;
  }
}

// ---------------- out-proj: M128xN128, 256 threads; A packed u32, B f32 ----
// Double-buffered (64 KB, 2 blocks/CU), ONE bar_lds per K-step, kt+2 prefetch.
__global__ __launch_bounds__(256) void k_outproj(
    const u32* __restrict__ ybp, const float* __restrict__ owf,
    float* __restrict__ out, int ib0)
{
  __shared__ __align__(16) u16 Ah[2][4*128*8], Al[2][4*128*8];
  __shared__ __align__(16) u16 Bh[2][4*128*8], Bl[2][4*128*8];
  const int tid = threadIdx.x;
  const int m0 = blockIdx.x << 7;
  const int n0 = blockIdx.y << 7;
  const int ib = ib0 + (m0 >> 10);
  const int i = ib >> 1, bb = ib & 1;
  const int il = i - (ib0 >> 1);
  const int ra = tid >> 1, half = tid & 1;   // A: 128 rows x 2 halves (16 u32)
  const u32* Ap = ybp + (size_t)(m0 + ra) * DI + half * 16;
  const int rb = tid >> 1;                   // B: same partition, 16 f32
  const float* Bpf = owf + ((size_t)il * DM + n0 + rb) * DI + half * 16;
  const int w = tid >> 6, lane = tid & 63;
  const int wr = w >> 1, wc = w & 1;
  const int l15 = lane & 15, l4 = lane >> 4;

  f32x4 acc[4][4];
  #pragma unroll
  for (int a_ = 0; a_ < 4; ++a_)
    #pragma unroll
    for (int b_ = 0; b_ < 4; ++b_) acc[a_][b_] = (f32x4)(0.f);

  uint4 qa[4];
  float br[16];
  auto LOADG = [&](int kt) {
    const int k0 = kt * 32;
    qa[0] = *(const uint4*)(Ap + k0);     qa[1] = *(const uint4*)(Ap + k0 + 4);
    qa[2] = *(const uint4*)(Ap + k0 + 8); qa[3] = *(const uint4*)(Ap + k0 + 12);
    #pragma unroll
    for (int q = 0; q < 4; ++q) *(f32x4*)&br[q*4] = *(const f32x4*)(Bpf + k0 + q*4);
  };
  auto STORE = [&](int b) {
    #pragma unroll
    for (int g = 0; g < 2; ++g) {
      const u32 e[8] = { qa[2*g].x, qa[2*g].y, qa[2*g].z, qa[2*g].w,
                         qa[2*g+1].x, qa[2*g+1].y, qa[2*g+1].z, qa[2*g+1].w };
      u16x8 vh, vl;
      #pragma unroll
      for (int c = 0; c < 8; ++c) { vh[c] = (u16)(e[c] >> 16); vl[c] = (u16)(e[c] & 0xffffu); }
      const int slot = ((half*2+g)*128 + ra)*8;
      *(u16x8*)&Ah[b][slot] = vh;
      *(u16x8*)&Al[b][slot] = vl;
    }
    stage16f<128>(br, Bh[b], Bl[b], rb, half);
  };
  auto COMPUTE = [&](int b) {
    bf16x8 ah[4], al[4];
    #pragma unroll
    for (int mf = 0; mf < 4; ++mf) {
      const int row = wr * 64 + mf * 16 + l15;
      ah[mf] = frag<128>(Ah[b], l4, row);
      al[mf] = frag<128>(Al[b], l4, row);
    }
    #pragma unroll
    for (int nf = 0; nf < 4; ++nf) {
      const int col = wc * 64 + nf * 16 + l15;
      bf16x8 bh = frag<128>(Bh[b], l4, col);
      bf16x8 bl = frag<128>(Bl[b], l4, col);
      #pragma unroll
      for (int mf = 0; mf < 4; ++mf) {
        acc[mf][nf] = __builtin_amdgcn_mfma_f32_16x16x32_bf16(ah[mf], bh, acc[mf][nf], 0, 0, 0);
        acc[mf][nf] = __builtin_amdgcn_mfma_f32_16x16x32_bf16(ah[mf], bl, acc[mf][nf], 0, 0, 0);
        acc[mf][nf] = __builtin_amdgcn_mfma_f32_16x16x32_bf16(al[mf], bh, acc[mf][nf], 0, 0, 0);
      }
    }
  };

  const int nk = DI / 32;   // 64
  LOADG(0);
  STORE(0);
  LOADG(1);
  bar_lds();
  for (int kt = 0; kt < nk; ++kt) {
    const int c = kt & 1;
    if (kt + 1 < nk) STORE(c ^ 1);
    if (kt + 2 < nk) LOADG(kt + 2);
    COMPUTE(c);
    bar_lds();
  }

  #pragma unroll
  for (int mf = 0; mf < 4; ++mf) {
    const int t0 = m0 + wr * 64 + mf * 16 + l4 * 4;
    #pragma unroll
    for (int nf = 0; nf < 4; ++nf) {
      const int col = n0 + wc * 64 + nf * 16 + l15;
      #pragma unroll
      for (int r = 0; r < 4; ++r) {
        const int j = (t0 + r) & (LS - 1);
        out[(size_t)(bb * 4096 + i * 1024 + j) * DM + col] = acc[mf][nf][r];
      }
    }
  }
}

extern "C" void kernel_launch(void* const* d_in, const int* in_sizes, int n_in,
                              void* d_out, int out_size, void* d_ws, size_t ws_size,
                              hipStream_t stream) {
  (void)in_sizes; (void)n_in; (void)out_size;
  const float* x       = (const float*)d_in[0];
  const float* in_w    = (const float*)d_in[1];
  const float* conv_w  = (const float*)d_in[2];
  const float* conv_b  = (const float*)d_in[3];
  const float* xproj_w = (const float*)d_in[4];
  const float* dt_w    = (const float*)d_in[5];
  const float* dt_b    = (const float*)d_in[6];
  const float* A_log   = (const float*)d_in[7];
  const float* D_skip  = (const float*)d_in[8];
  const float* out_w   = (const float*)d_in[9];
  float* out = (float*)d_out;
  const dim3 blk(256);

  // ---- single-pass: need = xz(134.2M) + xib(67.1M) + projb(3.1M) = 204,472,320 B
  const size_t needSP = ((size_t)8192 * 4096 + (size_t)8192 * 2048 + (size_t)8192 * 96) * 4;
  if (ws_size >= needSP) {
    const size_t nt = 8192;
    float* xz    = (float*)d_ws;
    float* xib   = xz + nt * (2 * DI);
    float* projb = xib + nt * DI;
    // d_out scratch (sequential lifetimes): x planes -> Pp -> P/H, then overwritten
    u16* xph  = (u16*)d_out;  u16* xpl  = xph + nt * DM;
    float* Pp = (float*)d_out;
    float* Pbuf = (float*)d_out;
    float* Hbuf = Pbuf + (size_t)8 * NCH * DSn * DI;
    float* dtz = xz;          // dt in x-half of xz rows, stride 4096
    u32* ybp  = (u32*)xib;    // packed y in-place over xi

    k_split_x<<<dim3((int)nt), blk, 0, stream>>>(x, xph, xpl, 0);
    k_inproj<<<dim3(2048), blk, 0, stream>>>(xph, xpl, in_w, xz, 0, 1);
    k_conv<<<dim3((int)(nt*(DI/4)/256)), blk, 0, stream>>>(xz, conv_w, conv_b, xib, 0, (int)nt);
    k_xproj_part<<<dim3((int)(nt/64), XKS), blk, 0, stream>>>(xib, xproj_w, Pp, 0, (int)nt);
    k_xproj_red<<<dim3((int)(nt*PW/256)), blk, 0, stream>>>(Pp, projb, (int)nt);
    k_dtproj<<<dim3(DI/128, (int)(nt/128)), blk, 0, stream>>>(projb, dt_w, dt_b, dtz, 2*DI, 0);
    k_scan_part<<<dim3(DI/256, NCH, 8), blk, 0, stream>>>(projb, dtz, 2*DI, xib, A_log, Pbuf, Hbuf, 0);
    k_scan_mid<<<dim3(8 * DSn * DI / 256), blk, 0, stream>>>(Pbuf, Hbuf, 8);
    k_scan_full<<<dim3(DI/256, NCH, 8), blk, 0, stream>>>(projb, dtz, 2*DI, xib, xz, A_log, D_skip, Pbuf, 0);
    k_outproj<<<dim3((int)(nt/128), 8), blk, 0, stream>>>(ybp, out_w, out, 0);
    return;
  }

  // ---- fallback: multi-pass, scratch entirely in d_ws ----
  auto needFB = [](int nib) -> size_t { return (size_t)nib * 29753344ull; };
  const int step = (ws_size >= needFB(4)) ? 4 : 2;

  for (int ib0 = 0; ib0 < 8; ib0 += step) {
    const int nib = step;
    const size_t nt = (size_t)nib * LS;
    const int i0 = ib0 >> 1;
    float* xz    = (float*)d_ws;
    float* xib   = xz + nt * (2 * DI);
    float* projb = xib + nt * DI;
    float* SH    = projb + nt * PW;
    u16* xph  = (u16*)SH;  u16* xpl = xph + nt * DM;
    float* Pp = SH;
    float* Pbuf = SH;
    float* Hbuf = Pbuf + (size_t)nib * NCH * DSn * DI / 2;
    float* dtz = xz;
    u32* ybp  = (u32*)xib;

    k_split_x<<<dim3((int)nt), blk, 0, stream>>>(x, xph, xpl, ib0);
    k_inproj<<<dim3((int)(nt/128), 32), blk, 0, stream>>>(xph, xpl, in_w + (size_t)i0*4096*DM, xz, ib0, 0);
    k_conv<<<dim3((int)(nt*(DI/4)/256)), blk, 0, stream>>>(xz, conv_w, conv_b, xib, ib0, (int)nt);
    k_xproj_part<<<dim3((int)(nt/64), XKS), blk, 0, stream>>>(xib, xproj_w + (size_t)i0*PW*DI, Pp, ib0, (int)nt);
    k_xproj_red<<<dim3((int)(nt*PW/256)), blk, 0, stream>>>(Pp, projb, (int)nt);
    k_dtproj<<<dim3(DI/128, (int)(nt/128)), blk, 0, stream>>>(projb, dt_w, dt_b, dtz, 2*DI, ib0);
    k_scan_part<<<dim3(DI/256, NCH, nib), blk, 0, stream>>>(projb, dtz, 2*DI, xib, A_log, Pbuf, Hbuf, ib0);
    k_scan_mid<<<dim3(nib * DSn * DI / 256), blk, 0, stream>>>(Pbuf, Hbuf, nib);
    k_scan_full<<<dim3(DI/256, NCH, nib), blk, 0, stream>>>(projb, dtz, 2*DI, xib, xz, A_log, D_skip, Pbuf, ib0);
    k_outproj<<<dim3((int)(nt/128), 8), blk, 0, stream>>>(ybp, out_w + (size_t)i0*DM*DI, out, ib0);
  }
}

// Round 9
// 602.241 us; speedup vs baseline: 1.0509x; 1.0509x over previous
//
#include <hip/hip_runtime.h>
#include <math.h>

#define DM   1024   // DMODEL
#define DI   2048   // D_INNER
#define DSn  16     // D_STATE
#define DTR  64     // DT_RANK
#define PW   96     // DT_RANK + 2*D_STATE
#define LS   1024   // per-mamba sequence length
#define NCH  16     // scan time-chunks
#define CL   64     // chunk length (LS/NCH)
#define XKS  4      // xproj K-slices

typedef unsigned short u16;
typedef unsigned int   u32;
typedef __attribute__((ext_vector_type(8))) short bf16x8;
typedef __attribute__((ext_vector_type(8))) unsigned short u16x8;
typedef __attribute__((ext_vector_type(4))) float f32x4;

// LDS-only barrier: waits ds-ops but leaves in-flight global loads un-drained.
__device__ __forceinline__ void bar_lds() {
  asm volatile("s_waitcnt lgkmcnt(0)\n\ts_barrier" ::: "memory");
}

// truncation hi/lo split: hi = trunc-to-bf16(f), lo = trunc-to-bf16(f - hi).
__device__ __forceinline__ void split2(float f, u16& hi, u16& lo) {
  union { float f; unsigned int u; } v; v.f = f;
  hi = (u16)(v.u >> 16);
  union { unsigned int u; float f; } w; w.u = v.u & 0xffff0000u;
  union { float f; unsigned int u; } r; r.f = f - w.f;
  lo = (u16)(r.u >> 16);
}

template<int ROWS>
__device__ __forceinline__ bf16x8 frag(const u16* T, int l4, int row) {
  return *(const bf16x8*)&T[(l4 * ROWS + row) * 8];
}

// stage 16 f32 into hi/lo planes (two k-groups of 8) at rows [ra], halves
template<int ROWS>
__device__ __forceinline__ void stage16f(const float* a, u16* Th, u16* Tl, int ra, int half) {
  #pragma unroll
  for (int q = 0; q < 2; ++q) {
    u16x8 vh, vl;
    #pragma unroll
    for (int c = 0; c < 8; ++c) {
      u16 h_, l_;
      split2(a[q * 8 + c], h_, l_);
      vh[c] = h_; vl[c] = l_;
    }
    const int slot = ((half * 2 + q) * ROWS + ra) * 8;
    *(u16x8*)&Th[slot] = vh;
    *(u16x8*)&Tl[slot] = vl;
  }
}

// x tokens -> token-ordered planes xh/xl [nt][1024] (local t)
__global__ __launch_bounds__(256) void k_split_x(
    const float* __restrict__ x, u16* __restrict__ xh, u16* __restrict__ xl, int ib0)
{
  const int idx = blockIdx.x * 256 + threadIdx.x;
  const int t = idx >> 8, kq = (idx & 255) * 4;
  const int gt = ib0 * 1024 + t;
  const int j = gt & (LS - 1), ib = gt >> 10;
  const int i = ib >> 1, bb = ib & 1;
  const float4 v = *(const float4*)&x[(size_t)(bb * 4096 + j * 4 + i) * DM + kq];
  ushort4 vh, vl;
  split2(v.x, vh.x, vl.x); split2(v.y, vh.y, vl.y);
  split2(v.z, vh.z, vl.z); split2(v.w, vh.w, vl.w);
  *(ushort4*)&xh[(size_t)t * DM + kq] = vh;
  *(ushort4*)&xl[(size_t)t * DM + kq] = vl;
}

// ---------------- in-proj: xz[t][e] = x_tok(t) . in_w[i][e]  (N=4096, K=1024)
// 256x256 tile, 512 threads (8 waves, wave owns 128x64). Double-buffered LDS,
// ONE lgkm-only barrier per K-step; global prefetch (kt+2) stays in flight
// across the barrier (no vmcnt drain). [measured best: 193 us, MfmaUtil 48]
#define KGP 2064    // u16 per k-group slice: 256*8 + 16 pad
__global__ __launch_bounds__(512, 2) void k_inproj(
    const u16* __restrict__ xh, const u16* __restrict__ xl,
    const float* __restrict__ inwf,
    float* __restrict__ xz, int ib0, int swz)
{
  // [buf][plane: Ah,Al,Bh,Bl][kgroup][2064 u16]  = 132096 B
  __shared__ __align__(16) u16 L[2][4][4][KGP];
  const int tid = threadIdx.x;
  int mblk, nblk;
  if (swz) {
    const int o = blockIdx.x;          // 0..511 = 32 mblk x 16 nblk
    const int xcd = o & 7, within = o >> 3;   // within 0..63
    mblk = xcd * 4 + (within & 3);     // each XCD owns one ib-block (4 mblks)
    nblk = within >> 2;                // 0..15
  } else {
    mblk = blockIdx.x; nblk = blockIdx.y;
  }
  const int m0 = mblk << 8, n0 = nblk << 8;
  const int ib = ib0 + (m0 >> 10);
  const int il = (ib >> 1) - (ib0 >> 1);
  const int ra = tid >> 1, half = tid & 1;      // 256 rows x 2 k-halves
  const u16* Aph = xh + (size_t)(m0 + ra) * DM + half * 16;
  const u16* Apl = xl + (size_t)(m0 + ra) * DM + half * 16;
  const float* Bpf = inwf + ((size_t)il * 4096 + n0 + ra) * DM + half * 16;
  const int w = tid >> 6, lane = tid & 63;
  const int wr = w >> 2, wc = w & 3;            // wave grid 2 x 4
  const int l15 = lane & 15, l4 = lane >> 4;

  f32x4 acc[8][4];
  #pragma unroll
  for (int a_ = 0; a_ < 8; ++a_)
    #pragma unroll
    for (int b_ = 0; b_ < 4; ++b_) acc[a_][b_] = (f32x4)(0.f);

  u16x8 ah2[2], al2[2];
  float br[16];

  auto LOADG = [&](int kt) {
    const int k0 = kt * 32;
    ah2[0] = *(const u16x8*)(Aph + k0);
    ah2[1] = *(const u16x8*)(Aph + k0 + 8);
    al2[0] = *(const u16x8*)(Apl + k0);
    al2[1] = *(const u16x8*)(Apl + k0 + 8);
    *(f32x4*)&br[0]  = *(const f32x4*)(Bpf + k0);
    *(f32x4*)&br[4]  = *(const f32x4*)(Bpf + k0 + 4);
    *(f32x4*)&br[8]  = *(const f32x4*)(Bpf + k0 + 8);
    *(f32x4*)&br[12] = *(const f32x4*)(Bpf + k0 + 12);
  };
  auto STORE = [&](int b) {
    #pragma unroll
    for (int q = 0; q < 2; ++q) {
      const int kg = half * 2 + q;
      *(u16x8*)&L[b][0][kg][ra * 8] = ah2[q];
      *(u16x8*)&L[b][1][kg][ra * 8] = al2[q];
      u16x8 vh, vl;
      #pragma unroll
      for (int c = 0; c < 8; ++c) {
        u16 h_, l_;
        split2(br[q * 8 + c], h_, l_);
        vh[c] = h_; vl[c] = l_;
      }
      *(u16x8*)&L[b][2][kg][ra * 8] = vh;
      *(u16x8*)&L[b][3][kg][ra * 8] = vl;
    }
  };
  auto COMPUTE = [&](int b) {
    bf16x8 bh[4], bl[4];
    #pragma unroll
    for (int nf = 0; nf < 4; ++nf) {
      const int col = wc * 64 + nf * 16 + l15;
      bh[nf] = *(const bf16x8*)&L[b][2][l4][col * 8];
      bl[nf] = *(const bf16x8*)&L[b][3][l4][col * 8];
    }
    #pragma unroll
    for (int mf = 0; mf < 8; ++mf) {
      const int row = wr * 128 + mf * 16 + l15;
      bf16x8 ah = *(const bf16x8*)&L[b][0][l4][row * 8];
      bf16x8 al = *(const bf16x8*)&L[b][1][l4][row * 8];
      #pragma unroll
      for (int nf = 0; nf < 4; ++nf) {
        acc[mf][nf] = __builtin_amdgcn_mfma_f32_16x16x32_bf16(ah, bh[nf], acc[mf][nf], 0, 0, 0);
        acc[mf][nf] = __builtin_amdgcn_mfma_f32_16x16x32_bf16(ah, bl[nf], acc[mf][nf], 0, 0, 0);
        acc[mf][nf] = __builtin_amdgcn_mfma_f32_16x16x32_bf16(al, bh[nf], acc[mf][nf], 0, 0, 0);
      }
    }
  };

  const int nk = DM / 32;   // 32
  // prologue: A(0)+B(0) into buf0; loads for kt=1 in flight across barrier
  LOADG(0);
  STORE(0);
  if (nk > 1) LOADG(1);
  bar_lds();
  for (int kt = 0; kt < nk; ++kt) {
    const int c = kt & 1;
    if (kt + 1 < nk) STORE(c ^ 1);        // stage kt+1 into other buffer
    if (kt + 2 < nk) LOADG(kt + 2);       // stays in flight across barrier
    COMPUTE(c);
    bar_lds();
  }

  #pragma unroll
  for (int mf = 0; mf < 8; ++mf) {
    const int row = m0 + wr * 128 + mf * 16 + l4 * 4;
    #pragma unroll
    for (int nf = 0; nf < 4; ++nf) {
      const int col = n0 + wc * 64 + nf * 16 + l15;
      #pragma unroll
      for (int r = 0; r < 4; ++r)
        xz[(size_t)(row + r) * (2 * DI) + col] = acc[mf][nf][r];
    }
  }
}

// ---------------- conv + silu -> xib f32 ----------------
__global__ __launch_bounds__(256) void k_conv(
    const float* __restrict__ xz, const float* __restrict__ convw,
    const float* __restrict__ convb, float* __restrict__ xib,
    int ib0, int ntok)
{
  const int idx = blockIdx.x * 256 + threadIdx.x;
  if (idx >= ntok * (DI / 4)) return;
  const int t = idx / (DI / 4);
  const int c = (idx - t * (DI / 4)) * 4;
  const int j = t & (LS - 1);
  const int i = (ib0 + (t >> 10)) >> 1;
  float4 acc = *(const float4*)&convb[(size_t)i * DI + c];
  float4 wt[4];
  #pragma unroll
  for (int q = 0; q < 4; ++q)
    wt[q] = *(const float4*)&convw[((size_t)i * DI + c + q) * 4];
  #pragma unroll
  for (int k = 0; k < 4; ++k) {
    const int j2 = j + k - 3;
    if (j2 >= 0) {
      const float4 v = *(const float4*)&xz[(size_t)(t + k - 3) * (2 * DI) + c];
      acc.x = fmaf(v.x, ((const float*)&wt[0])[k], acc.x);
      acc.y = fmaf(v.y, ((const float*)&wt[1])[k], acc.y);
      acc.z = fmaf(v.z, ((const float*)&wt[2])[k], acc.z);
      acc.w = fmaf(v.w, ((const float*)&wt[3])[k], acc.w);
    }
  }
  float4 o;
  o.x = acc.x / (1.f + __expf(-acc.x));
  o.y = acc.y / (1.f + __expf(-acc.y));
  o.z = acc.z / (1.f + __expf(-acc.z));
  o.w = acc.w / (1.f + __expf(-acc.w));
  *(float4*)&xib[(size_t)t * DI + c] = o;
}

// ---------------- xproj part: A from xi f32, B from xproj_w f32 ------------
// Double-buffered (40 KB), ONE bar_lds per K-step, kt+2 reg prefetch.
__global__ __launch_bounds__(256) void k_xproj_part(
    const float* __restrict__ xif, const float* __restrict__ xwf,
    float* __restrict__ Pp, int ib0, int ntok)
{
  __shared__ __align__(16) u16 Ah[2][4*64*8], Al[2][4*64*8];
  __shared__ __align__(16) u16 Bh[2][4*96*8], Bl[2][4*96*8];
  const int tid = threadIdx.x;
  const int m0 = blockIdx.x << 6;
  const int ks = blockIdx.y;
  const int kbase = ks * (DI / XKS);
  const int ib = ib0 + (m0 >> 10);
  const int il = (ib >> 1) - (ib0 >> 1);
  const int ra = tid >> 1, half = tid & 1;
  const bool hasA = (tid < 128);
  const bool hasB = (tid < 192);
  const float* Apf = xif + (size_t)(m0 + ra) * DI + kbase + half * 16;
  const float* Bpf = xwf + ((size_t)il * PW + ra) * DI + kbase + half * 16;
  const int w = tid >> 6, lane = tid & 63;
  const int l15 = lane & 15, l4 = lane >> 4;

  f32x4 acc[6];
  #pragma unroll
  for (int b_ = 0; b_ < 6; ++b_) acc[b_] = (f32x4)(0.f);

  float ar[16], br[16];
  auto LOADAB = [&](int kt) {
    const int k0 = kt * 32;
    if (hasA) {
      #pragma unroll
      for (int q = 0; q < 4; ++q) *(f32x4*)&ar[q*4] = *(const f32x4*)(Apf + k0 + q*4);
    }
    if (hasB) {
      #pragma unroll
      for (int q = 0; q < 4; ++q) *(f32x4*)&br[q*4] = *(const f32x4*)(Bpf + k0 + q*4);
    }
  };
  auto STORE = [&](int b) {
    if (hasA) stage16f<64>(ar, Ah[b], Al[b], ra, half);
    if (hasB) stage16f<96>(br, Bh[b], Bl[b], ra, half);
  };
  auto COMPUTE = [&](int b) {
    const int arow = w * 16 + l15;
    bf16x8 ah = frag<64>(Ah[b], l4, arow);
    bf16x8 al = frag<64>(Al[b], l4, arow);
    #pragma unroll
    for (int nf = 0; nf < 6; ++nf) {
      const int col = nf * 16 + l15;
      bf16x8 bh = frag<96>(Bh[b], l4, col);
      bf16x8 bl = frag<96>(Bl[b], l4, col);
      acc[nf] = __builtin_amdgcn_mfma_f32_16x16x32_bf16(ah, bh, acc[nf], 0, 0, 0);
      acc[nf] = __builtin_amdgcn_mfma_f32_16x16x32_bf16(ah, bl, acc[nf], 0, 0, 0);
      acc[nf] = __builtin_amdgcn_mfma_f32_16x16x32_bf16(al, bh, acc[nf], 0, 0, 0);
    }
  };

  const int nk = (DI / XKS) / 32;   // 16
  LOADAB(0);
  STORE(0);
  LOADAB(1);
  bar_lds();
  for (int kt = 0; kt < nk; ++kt) {
    const int c = kt & 1;
    if (kt + 1 < nk) STORE(c ^ 1);
    if (kt + 2 < nk) LOADAB(kt + 2);
    COMPUTE(c);
    bar_lds();
  }

  float* outp = Pp + (size_t)ks * ntok * PW;
  const int row = m0 + w * 16 + l4 * 4;
  #pragma unroll
  for (int nf = 0; nf < 6; ++nf) {
    const int col = nf * 16 + l15;
    #pragma unroll
    for (int r = 0; r < 4; ++r)
      outp[(size_t)(row + r) * PW + col] = acc[nf][r];
  }
}

// ---------------- xproj reduce ----------------
__global__ __launch_bounds__(256) void k_xproj_red(
    const float* __restrict__ Pp, float* __restrict__ projb, int ntok)
{
  const int idx = blockIdx.x * 256 + threadIdx.x;
  if (idx >= ntok * PW) return;
  const size_t plane = (size_t)ntok * PW;
  float s = 0.f;
  #pragma unroll
  for (int ks = 0; ks < XKS; ++ks) s += Pp[(size_t)ks * plane + idx];
  projb[idx] = s;
}

// ---------------- dt GEMM (MFMA hi/lo) + softplus -> dtout[t*dstride + d] --
// M=ntok (by: 128-token tile), N=DI (bx: 128-d tile), K=DTR=64.
// Single staging pass (K fits in LDS), one barrier, 96 MFMA/wave.
__global__ __launch_bounds__(256) void k_dtproj(
    const float* __restrict__ proj, const float* __restrict__ dtw,
    const float* __restrict__ dtbias, float* __restrict__ dtout,
    int dstride, int ib0)
{
  __shared__ __align__(16) u16 Ah[8*128*8], Al[8*128*8];   // 16 KB each
  __shared__ __align__(16) u16 Bh[8*128*8], Bl[8*128*8];
  const int tid = threadIdx.x;
  const int n0 = blockIdx.x << 7;
  const int m0 = blockIdx.y << 7;
  const int ib = ib0 + (m0 >> 10);
  const int i  = ib >> 1;
  const int ra = tid >> 1, half = tid & 1;   // 128 rows x 2 k-halves (32 each)
  const float* Ap = proj + (size_t)(m0 + ra) * PW + half * 32;
  const float* Bp = dtw + ((size_t)i * DI + n0 + ra) * DTR + half * 32;
  const int w = tid >> 6, lane = tid & 63;
  const int wr = w >> 1, wc = w & 1;         // wave grid 2 x 2, wave owns 64x64
  const int l15 = lane & 15, l4 = lane >> 4;

  {
    float av[32], bv[32];
    #pragma unroll
    for (int q = 0; q < 8; ++q) *(f32x4*)&av[q*4] = *(const f32x4*)(Ap + q*4);
    #pragma unroll
    for (int q = 0; q < 8; ++q) *(f32x4*)&bv[q*4] = *(const f32x4*)(Bp + q*4);
    #pragma unroll
    for (int q = 0; q < 4; ++q) {
      u16x8 vh, vl, wh, wl;
      #pragma unroll
      for (int c = 0; c < 8; ++c) {
        u16 h_, l_;
        split2(av[q*8+c], h_, l_); vh[c] = h_; vl[c] = l_;
        split2(bv[q*8+c], h_, l_); wh[c] = h_; wl[c] = l_;
      }
      const int slot = ((half*4 + q) * 128 + ra) * 8;
      *(u16x8*)&Ah[slot] = vh; *(u16x8*)&Al[slot] = vl;
      *(u16x8*)&Bh[slot] = wh; *(u16x8*)&Bl[slot] = wl;
    }
  }
  __syncthreads();

  f32x4 acc[4][4];
  #pragma unroll
  for (int a_ = 0; a_ < 4; ++a_)
    #pragma unroll
    for (int b_ = 0; b_ < 4; ++b_) acc[a_][b_] = (f32x4)(0.f);

  #pragma unroll
  for (int c = 0; c < 2; ++c) {              // K-chunk of 32: kgroups 4c+l4
    bf16x8 bh[4], bl[4];
    #pragma unroll
    for (int nf = 0; nf < 4; ++nf) {
      const int col = wc * 64 + nf * 16 + l15;
      bh[nf] = *(const bf16x8*)&Bh[((4*c + l4) * 128 + col) * 8];
      bl[nf] = *(const bf16x8*)&Bl[((4*c + l4) * 128 + col) * 8];
    }
    #pragma unroll
    for (int mf = 0; mf < 4; ++mf) {
      const int row = wr * 64 + mf * 16 + l15;
      bf16x8 ah = *(const bf16x8*)&Ah[((4*c + l4) * 128 + row) * 8];
      bf16x8 al = *(const bf16x8*)&Al[((4*c + l4) * 128 + row) * 8];
      #pragma unroll
      for (int nf = 0; nf < 4; ++nf) {
        acc[mf][nf] = __builtin_amdgcn_mfma_f32_16x16x32_bf16(ah, bh[nf], acc[mf][nf], 0, 0, 0);
        acc[mf][nf] = __builtin_amdgcn_mfma_f32_16x16x32_bf16(ah, bl[nf], acc[mf][nf], 0, 0, 0);
        acc[mf][nf] = __builtin_amdgcn_mfma_f32_16x16x32_bf16(al, bh[nf], acc[mf][nf], 0, 0, 0);
      }
    }
  }

  #pragma unroll
  for (int nf = 0; nf < 4; ++nf) {
    const int col = n0 + wc * 64 + nf * 16 + l15;
    const float bias = dtbias[(size_t)i * DI + col];
    #pragma unroll
    for (int mf = 0; mf < 4; ++mf) {
      const int t0 = m0 + wr * 64 + mf * 16 + l4 * 4;
      #pragma unroll
      for (int r = 0; r < 4; ++r) {
        const float u = acc[mf][nf][r] + bias;
        const float sp = (u > 20.f) ? u : log1pf(__expf(u));
        dtout[(size_t)(t0 + r) * dstride + col] = sp;
      }
    }
  }
}

// ---------------- scan phase A ----------------
__global__ __launch_bounds__(256) void k_scan_part(
    const float* __restrict__ projb, const float* dtp, int dstride,
    const float* __restrict__ xib, const float* __restrict__ A_log,
    float* __restrict__ Pbuf, float* __restrict__ Hbuf, int ib0)
{
  const int d = blockIdx.x * 256 + threadIdx.x;
  const int ch = blockIdx.y, lib = blockIdx.z;
  const int i = (ib0 + lib) >> 1;
  const size_t gd = (size_t)i * DI + d;
  __shared__ float bs[CL][DSn];
  const size_t trow = (size_t)lib * LS + (size_t)ch * CL;
  for (int p = threadIdx.x; p < CL * DSn; p += 256) {
    const int jj = p >> 4, ss = p & 15;
    bs[jj][ss] = projb[(trow + jj) * PW + DTR + ss];
  }
  float A[DSn], P[DSn], h[DSn];
  #pragma unroll
  for (int s = 0; s < DSn; ++s) {
    A[s] = -__expf(A_log[gd * DSn + s]);
    P[s] = 1.f; h[s] = 0.f;
  }
  __syncthreads();
  float dt_c = dtp[trow * dstride + d];
  float xi_c = xib[trow * DI + d];
  for (int j = 0; j < CL; ++j) {
    float dt_n = 0.f, xi_n = 0.f;
    if (j + 1 < CL) {
      dt_n = dtp[(trow + j + 1) * dstride + d];
      xi_n = xib[(trow + j + 1) * DI + d];
    }
    const float dx = dt_c * xi_c;
    #pragma unroll
    for (int s = 0; s < DSn; ++s) {
      const float dA = __expf(dt_c * A[s]);
      P[s] *= dA;
      h[s] = fmaf(dA, h[s], dx * bs[j][s]);
    }
    dt_c = dt_n; xi_c = xi_n;
  }
  const size_t base = ((size_t)(lib * NCH + ch) * DSn) * DI + d;
  #pragma unroll
  for (int s = 0; s < DSn; ++s) {
    Pbuf[base + (size_t)s * DI] = P[s];
    Hbuf[base + (size_t)s * DI] = h[s];
  }
}

// ---------------- scan phase B ----------------
__global__ __launch_bounds__(256) void k_scan_mid(
    float* __restrict__ Pbuf, const float* __restrict__ Hbuf, int nib)
{
  const int idx = blockIdx.x * 256 + threadIdx.x;
  if (idx >= nib * DSn * DI) return;
  const int d = idx & (DI - 1);
  const int s = (idx >> 11) & 15;
  const int lib = idx >> 15;
  const size_t stride = (size_t)DSn * DI;
  const size_t base = ((size_t)lib * NCH * DSn + s) * DI + d;
  float carry = 0.f;
  for (int c = 0; c < NCH; ++c) {
    const size_t o = base + (size_t)c * stride;
    const float p = Pbuf[o];
    const float hl = Hbuf[o];
    Pbuf[o] = carry;
    carry = fmaf(p, carry, hl);
  }
}

// ---------------- scan phase C: gated y packed (bf16 hi|lo) IN-PLACE over xi
__global__ __launch_bounds__(256) void k_scan_full(
    const float* __restrict__ projb, const float* dtp, int dstride,
    float* xibio, const float* xzz,
    const float* __restrict__ A_log, const float* __restrict__ D_skip,
    const float* __restrict__ Pbuf, int ib0)
{
  const int d = blockIdx.x * 256 + threadIdx.x;
  const int ch = blockIdx.y, lib = blockIdx.z;
  const int i = (ib0 + lib) >> 1;
  const size_t gd = (size_t)i * DI + d;
  __shared__ float bs[CL][2 * DSn];
  const size_t trow = (size_t)lib * LS + (size_t)ch * CL;
  for (int p = threadIdx.x; p < CL * 2 * DSn; p += 256) {
    const int jj = p >> 5, ss = p & 31;
    bs[jj][ss] = projb[(trow + jj) * PW + DTR + ss];
  }
  float A[DSn], h[DSn];
  const size_t hbase = ((size_t)(lib * NCH + ch) * DSn) * DI + d;
  #pragma unroll
  for (int s = 0; s < DSn; ++s) {
    A[s] = -__expf(A_log[gd * DSn + s]);
    h[s] = Pbuf[hbase + (size_t)s * DI];
  }
  const float Dsk = D_skip[gd];
  __syncthreads();
  float dt_c = dtp[trow * dstride + d];
  float xi_c = xibio[trow * DI + d];
  float z_c  = xzz[trow * (2 * DI) + DI + d];
  for (int j = 0; j < CL; ++j) {
    float dt_n = 0.f, xi_n = 0.f, z_n = 0.f;
    if (j + 1 < CL) {
      dt_n = dtp[(trow + j + 1) * dstride + d];
      xi_n = xibio[(trow + j + 1) * DI + d];
      z_n  = xzz[(trow + j + 1) * (2 * DI) + DI + d];
    }
    const float dx = dt_c * xi_c;
    float y = 0.f;
    #pragma unroll
    for (int s = 0; s < DSn; ++s) {
      const float dA = __expf(dt_c * A[s]);
      h[s] = fmaf(dA, h[s], dx * bs[j][s]);
      y = fmaf(h[s], bs[j][DSn + s], y);
    }
    const float sz = z_c / (1.f + __expf(-z_c));
    const float val = (y + xi_c * Dsk) * sz;
    u16 vh, vl;
    split2(val, vh, vl);
    ((u32*)xibio)[(trow + j) * DI + d] = ((u32)vh << 16) | (u32)vl;
    dt_c = dt_n; xi_c = xi_n; z_c = z_n;
  }
}

// ---------------- out-proj: M128xN128, 256 threads; A packed u32, B f32 ----
// Double-buffered (64 KB, 2 blocks/CU), ONE bar_lds per K-step, kt+2 prefetch.
// XCD-chunked swizzle (T1): each XCD owns 8 consecutive m-tiles x all 8 n —
// the 1 MB ybp A-tile becomes an XCD-L2 hit for its 8 co-resident n-blocks.
__global__ __launch_bounds__(256) void k_outproj(
    const u32* __restrict__ ybp, const float* __restrict__ owf,
    float* __restrict__ out, int ib0, int swz)
{
  __shared__ __align__(16) u16 Ah[2][4*128*8], Al[2][4*128*8];
  __shared__ __align__(16) u16 Bh[2][4*128*8], Bl[2][4*128*8];
  const int tid = threadIdx.x;
  int mblk, nblk;
  if (swz) {
    const int o = blockIdx.x;          // 0..511 = 64 mblk x 8 nblk
    const int xcd = o & 7, wi = o >> 3;       // wi 0..63
    mblk = xcd * 8 + (wi & 7);         // 8 consecutive m-tiles per XCD
    nblk = wi >> 3;                    // 0..7
  } else {
    mblk = blockIdx.x; nblk = blockIdx.y;
  }
  const int m0 = mblk << 7;
  const int n0 = nblk << 7;
  const int ib = ib0 + (m0 >> 10);
  const int i = ib >> 1, bb = ib & 1;
  const int il = i - (ib0 >> 1);
  const int ra = tid >> 1, half = tid & 1;   // A: 128 rows x 2 halves (16 u32)
  const u32* Ap = ybp + (size_t)(m0 + ra) * DI + half * 16;
  const int rb = tid >> 1;                   // B: same partition, 16 f32
  const float* Bpf = owf + ((size_t)il * DM + n0 + rb) * DI + half * 16;
  const int w = tid >> 6, lane = tid & 63;
  const int wr = w >> 1, wc = w & 1;
  const int l15 = lane & 15, l4 = lane >> 4;

  f32x4 acc[4][4];
  #pragma unroll
  for (int a_ = 0; a_ < 4; ++a_)
    #pragma unroll
    for (int b_ = 0; b_ < 4; ++b_) acc[a_][b_] = (f32x4)(0.f);

  uint4 qa[4];
  float br[16];
  auto LOADG = [&](int kt) {
    const int k0 = kt * 32;
    qa[0] = *(const uint4*)(Ap + k0);     qa[1] = *(const uint4*)(Ap + k0 + 4);
    qa[2] = *(const uint4*)(Ap + k0 + 8); qa[3] = *(const uint4*)(Ap + k0 + 12);
    #pragma unroll
    for (int q = 0; q < 4; ++q) *(f32x4*)&br[q*4] = *(const f32x4*)(Bpf + k0 + q*4);
  };
  auto STORE = [&](int b) {
    #pragma unroll
    for (int g = 0; g < 2; ++g) {
      const u32 e[8] = { qa[2*g].x, qa[2*g].y, qa[2*g].z, qa[2*g].w,
                         qa[2*g+1].x, qa[2*g+1].y, qa[2*g+1].z, qa[2*g+1].w };
      u16x8 vh, vl;
      #pragma unroll
      for (int c = 0; c < 8; ++c) { vh[c] = (u16)(e[c] >> 16); vl[c] = (u16)(e[c] & 0xffffu); }
      const int slot = ((half*2+g)*128 + ra)*8;
      *(u16x8*)&Ah[b][slot] = vh;
      *(u16x8*)&Al[b][slot] = vl;
    }
    stage16f<128>(br, Bh[b], Bl[b], rb, half);
  };
  auto COMPUTE = [&](int b) {
    bf16x8 ah[4], al[4];
    #pragma unroll
    for (int mf = 0; mf < 4; ++mf) {
      const int row = wr * 64 + mf * 16 + l15;
      ah[mf] = frag<128>(Ah[b], l4, row);
      al[mf] = frag<128>(Al[b], l4, row);
    }
    #pragma unroll
    for (int nf = 0; nf < 4; ++nf) {
      const int col = wc * 64 + nf * 16 + l15;
      bf16x8 bh = frag<128>(Bh[b], l4, col);
      bf16x8 bl = frag<128>(Bl[b], l4, col);
      #pragma unroll
      for (int mf = 0; mf < 4; ++mf) {
        acc[mf][nf] = __builtin_amdgcn_mfma_f32_16x16x32_bf16(ah[mf], bh, acc[mf][nf], 0, 0, 0);
        acc[mf][nf] = __builtin_amdgcn_mfma_f32_16x16x32_bf16(ah[mf], bl, acc[mf][nf], 0, 0, 0);
        acc[mf][nf] = __builtin_amdgcn_mfma_f32_16x16x32_bf16(al[mf], bh, acc[mf][nf], 0, 0, 0);
      }
    }
  };

  const int nk = DI / 32;   // 64
  LOADG(0);
  STORE(0);
  LOADG(1);
  bar_lds();
  for (int kt = 0; kt < nk; ++kt) {
    const int c = kt & 1;
    if (kt + 1 < nk) STORE(c ^ 1);
    if (kt + 2 < nk) LOADG(kt + 2);
    COMPUTE(c);
    bar_lds();
  }

  #pragma unroll
  for (int mf = 0; mf < 4; ++mf) {
    const int t0 = m0 + wr * 64 + mf * 16 + l4 * 4;
    #pragma unroll
    for (int nf = 0; nf < 4; ++nf) {
      const int col = n0 + wc * 64 + nf * 16 + l15;
      #pragma unroll
      for (int r = 0; r < 4; ++r) {
        const int j = (t0 + r) & (LS - 1);
        out[(size_t)(bb * 4096 + i * 1024 + j) * DM + col] = acc[mf][nf][r];
      }
    }
  }
}

extern "C" void kernel_launch(void* const* d_in, const int* in_sizes, int n_in,
                              void* d_out, int out_size, void* d_ws, size_t ws_size,
                              hipStream_t stream) {
  (void)in_sizes; (void)n_in; (void)out_size;
  const float* x       = (const float*)d_in[0];
  const float* in_w    = (const float*)d_in[1];
  const float* conv_w  = (const float*)d_in[2];
  const float* conv_b  = (const float*)d_in[3];
  const float* xproj_w = (const float*)d_in[4];
  const float* dt_w    = (const float*)d_in[5];
  const float* dt_b    = (const float*)d_in[6];
  const float* A_log   = (const float*)d_in[7];
  const float* D_skip  = (const float*)d_in[8];
  const float* out_w   = (const float*)d_in[9];
  float* out = (float*)d_out;
  const dim3 blk(256);

  // ---- single-pass: need = xz(134.2M) + xib(67.1M) + projb(3.1M) = 204,472,320 B
  const size_t needSP = ((size_t)8192 * 4096 + (size_t)8192 * 2048 + (size_t)8192 * 96) * 4;
  if (ws_size >= needSP) {
    const size_t nt = 8192;
    float* xz    = (float*)d_ws;
    float* xib   = xz + nt * (2 * DI);
    float* projb = xib + nt * DI;
    // d_out scratch (sequential lifetimes): x planes -> Pp -> P/H, then overwritten
    u16* xph  = (u16*)d_out;  u16* xpl  = xph + nt * DM;
    float* Pp = (float*)d_out;
    float* Pbuf = (float*)d_out;
    float* Hbuf = Pbuf + (size_t)8 * NCH * DSn * DI;
    float* dtz = xz;          // dt in x-half of xz rows, stride 4096
    u32* ybp  = (u32*)xib;    // packed y in-place over xi

    k_split_x<<<dim3((int)nt), blk, 0, stream>>>(x, xph, xpl, 0);
    k_inproj<<<dim3(512), dim3(512), 0, stream>>>(xph, xpl, in_w, xz, 0, 1);
    k_conv<<<dim3((int)(nt*(DI/4)/256)), blk, 0, stream>>>(xz, conv_w, conv_b, xib, 0, (int)nt);
    k_xproj_part<<<dim3((int)(nt/64), XKS), blk, 0, stream>>>(xib, xproj_w, Pp, 0, (int)nt);
    k_xproj_red<<<dim3((int)(nt*PW/256)), blk, 0, stream>>>(Pp, projb, (int)nt);
    k_dtproj<<<dim3(DI/128, (int)(nt/128)), blk, 0, stream>>>(projb, dt_w, dt_b, dtz, 2*DI, 0);
    k_scan_part<<<dim3(DI/256, NCH, 8), blk, 0, stream>>>(projb, dtz, 2*DI, xib, A_log, Pbuf, Hbuf, 0);
    k_scan_mid<<<dim3(8 * DSn * DI / 256), blk, 0, stream>>>(Pbuf, Hbuf, 8);
    k_scan_full<<<dim3(DI/256, NCH, 8), blk, 0, stream>>>(projb, dtz, 2*DI, xib, xz, A_log, D_skip, Pbuf, 0);
    k_outproj<<<dim3(512), blk, 0, stream>>>(ybp, out_w, out, 0, 1);
    return;
  }

  // ---- fallback: multi-pass, scratch entirely in d_ws ----
  auto needFB = [](int nib) -> size_t { return (size_t)nib * 29753344ull; };
  const int step = (ws_size >= needFB(4)) ? 4 : 2;

  for (int ib0 = 0; ib0 < 8; ib0 += step) {
    const int nib = step;
    const size_t nt = (size_t)nib * LS;
    const int i0 = ib0 >> 1;
    float* xz    = (float*)d_ws;
    float* xib   = xz + nt * (2 * DI);
    float* projb = xib + nt * DI;
    float* SH    = projb + nt * PW;
    u16* xph  = (u16*)SH;  u16* xpl = xph + nt * DM;
    float* Pp = SH;
    float* Pbuf = SH;
    float* Hbuf = Pbuf + (size_t)nib * NCH * DSn * DI / 2;
    float* dtz = xz;
    u32* ybp  = (u32*)xib;

    k_split_x<<<dim3((int)nt), blk, 0, stream>>>(x, xph, xpl, ib0);
    k_inproj<<<dim3((int)(nt/256), 16), dim3(512), 0, stream>>>(xph, xpl, in_w + (size_t)i0*4096*DM, xz, ib0, 0);
    k_conv<<<dim3((int)(nt*(DI/4)/256)), blk, 0, stream>>>(xz, conv_w, conv_b, xib, ib0, (int)nt);
    k_xproj_part<<<dim3((int)(nt/64), XKS), blk, 0, stream>>>(xib, xproj_w + (size_t)i0*PW*DI, Pp, ib0, (int)nt);
    k_xproj_red<<<dim3((int)(nt*PW/256)), blk, 0, stream>>>(Pp, projb, (int)nt);
    k_dtproj<<<dim3(DI/128, (int)(nt/128)), blk, 0, stream>>>(projb, dt_w, dt_b, dtz, 2*DI, ib0);
    k_scan_part<<<dim3(DI/256, NCH, nib), blk, 0, stream>>>(projb, dtz, 2*DI, xib, A_log, Pbuf, Hbuf, ib0);
    k_scan_mid<<<dim3(nib * DSn * DI / 256), blk, 0, stream>>>(Pbuf, Hbuf, nib);
    k_scan_full<<<dim3(DI/256, NCH, nib), blk, 0, stream>>>(projb, dtz, 2*DI, xib, xz, A_log, D_skip, Pbuf, ib0);
    k_outproj<<<dim3((int)(nt/128), 8), blk, 0, stream>>>(ybp, out_w + (size_t)i0*DM*DI, out, ib0, 0);
  }
}